// Round 1
// baseline (2417.300 us; speedup 1.0000x reference)
//
#include <hip/hip_runtime.h>

// Chunked causal linear attention, f32 baseline.
// B=4 H=8 N=8192 D=E=64 C=128. 3 kernels:
//  1) chunk_states: per-chunk totals {sumK, sumKr, K^T V, Kr^T V} -> ws
//  2) scan_states : exclusive prefix over 64 chunks per (b,h) in-place; totals -> d_out tail
//  3) chunk_out   : P = tril(QK^T + QrKr^T); out = (P V + Q Sc + Qr Scr) / (rowsum(P)+q.kc+qr.krc+eps)
// ws requirement: 2048 * 8320 * 4 = 68,157,440 bytes.

constexpr int B_ = 4, H_ = 8, BH = 32;
constexpr int N_ = 8192, D_ = 64, E_ = 64, C_ = 128;
constexpr int NC = 64;               // chunks per (b,h)
constexpr int NCHUNKS = BH * NC;     // 2048
constexpr int STATE = 64 + 64 + 64 * 64 + 64 * 64;  // 8320 floats per chunk-state
#define EPS_ 1e-6f

constexpr size_t OUT_ELEMS = (size_t)BH * N_ * E_;      // 16777216
constexpr size_t ZOFF  = OUT_ELEMS;                      // Z      (BH*64)
constexpr size_t SOFF  = ZOFF  + (size_t)BH * 64;        // S      (BH*4096)
constexpr size_t ZROFF = SOFF  + (size_t)BH * 4096;      // Z_rot
constexpr size_t SROFF = ZROFF + (size_t)BH * 64;        // S_rot

// ---------------- Phase 1: per-chunk state totals ----------------
__global__ __launch_bounds__(256) void chunk_states(
    const float* __restrict__ gk, const float* __restrict__ gkr,
    const float* __restrict__ gv, float* __restrict__ ws)
{
    __shared__ float sk[32][68], skr[32][68], sv[32][68];
    const int t = threadIdx.x;
    const int cid = blockIdx.x;            // 0..2047
    const int bh = cid >> 6;
    const int c  = cid & 63;
    const size_t gbase = (size_t)bh * N_ * D_ + (size_t)c * C_ * D_;

    const int d2 = t >> 3;                 // 0..31 -> handles d2 and d2+32
    const int e0 = (t & 7) * 8;            // 0..56

    float acc0[8], acc1[8], accr0[8], accr1[8];
#pragma unroll
    for (int j = 0; j < 8; ++j) { acc0[j]=0.f; acc1[j]=0.f; accr0[j]=0.f; accr1[j]=0.f; }
    float sumk = 0.f;                      // t<64: sumK[t]; t in [64,128): sumKr[t-64]

    for (int mt = 0; mt < 4; ++mt) {
        const int m0 = mt * 32;
        // stage 32x64 tiles of k, kr, v
#pragma unroll
        for (int i = 0; i < 2; ++i) {
            int fi = i * 256 + t;          // 512 float4s
            int row = fi >> 4, c4 = (fi & 15) * 4;
            const size_t g = gbase + (size_t)(m0 + row) * D_ + c4;
            *(float4*)&sk [row][c4] = *(const float4*)(gk  + g);
            *(float4*)&skr[row][c4] = *(const float4*)(gkr + g);
            *(float4*)&sv [row][c4] = *(const float4*)(gv  + g);
        }
        __syncthreads();
#pragma unroll 4
        for (int m = 0; m < 32; ++m) {
            const float kd0  = sk [m][d2], kd1  = sk [m][d2 + 32];
            const float krd0 = skr[m][d2], krd1 = skr[m][d2 + 32];
            const float4 va = *(const float4*)&sv[m][e0];
            const float4 vb = *(const float4*)&sv[m][e0 + 4];
            const float vv[8] = {va.x,va.y,va.z,va.w, vb.x,vb.y,vb.z,vb.w};
#pragma unroll
            for (int j = 0; j < 8; ++j) {
                acc0 [j] += kd0  * vv[j];
                acc1 [j] += kd1  * vv[j];
                accr0[j] += krd0 * vv[j];
                accr1[j] += krd1 * vv[j];
            }
        }
        if (t < 64) {
            for (int m = 0; m < 32; ++m) sumk += sk[m][t];
        } else if (t < 128) {
            const int d = t - 64;
            for (int m = 0; m < 32; ++m) sumk += skr[m][d];
        }
        __syncthreads();
    }

    float* st = ws + (size_t)cid * STATE;
    if (t < 128) st[t] = sumk;             // [0,64)=sumK, [64,128)=sumKr
    float* cs  = st + 128;
    float* csr = st + 128 + 64 * 64;
    *(float4*)&cs [d2 * 64 + e0]            = make_float4(acc0[0], acc0[1], acc0[2], acc0[3]);
    *(float4*)&cs [d2 * 64 + e0 + 4]        = make_float4(acc0[4], acc0[5], acc0[6], acc0[7]);
    *(float4*)&cs [(d2 + 32) * 64 + e0]     = make_float4(acc1[0], acc1[1], acc1[2], acc1[3]);
    *(float4*)&cs [(d2 + 32) * 64 + e0 + 4] = make_float4(acc1[4], acc1[5], acc1[6], acc1[7]);
    *(float4*)&csr[d2 * 64 + e0]            = make_float4(accr0[0], accr0[1], accr0[2], accr0[3]);
    *(float4*)&csr[d2 * 64 + e0 + 4]        = make_float4(accr0[4], accr0[5], accr0[6], accr0[7]);
    *(float4*)&csr[(d2 + 32) * 64 + e0]     = make_float4(accr1[0], accr1[1], accr1[2], accr1[3]);
    *(float4*)&csr[(d2 + 32) * 64 + e0 + 4] = make_float4(accr1[4], accr1[5], accr1[6], accr1[7]);
}

// ---------------- Phase 2: exclusive scan over chunks; totals -> out tail ----------------
__global__ __launch_bounds__(256) void scan_states(float* __restrict__ ws, float* __restrict__ out)
{
    const int bh = blockIdx.x;
    const int j  = blockIdx.y * 256 + threadIdx.x;
    if (j >= STATE) return;
    float run = 0.f;
    const size_t base = (size_t)bh * NC * STATE + j;
#pragma unroll 4
    for (int c = 0; c < NC; ++c) {
        const size_t idx = base + (size_t)c * STATE;
        const float x = ws[idx];
        ws[idx] = run;                     // exclusive prefix = carry-in for chunk c
        run += x;
    }
    // inclusive total = final-state outputs
    if (j < 64)        out[ZOFF  + (size_t)bh * 64   + j]          = run;
    else if (j < 128)  out[ZROFF + (size_t)bh * 64   + (j - 64)]   = run;
    else if (j < 4224) out[SOFF  + (size_t)bh * 4096 + (j - 128)]  = run;
    else               out[SROFF + (size_t)bh * 4096 + (j - 4224)] = run;
}

// ---------------- Phase 3: per-chunk output ----------------
// grid: 2 row-blocks (64 rows) per chunk. m-tile = 32, d staged in halves of 32.
__global__ __launch_bounds__(256) void chunk_out(
    const float* __restrict__ gq, const float* __restrict__ gqr,
    const float* __restrict__ gk, const float* __restrict__ gkr,
    const float* __restrict__ gv, const float* __restrict__ ws,
    float* __restrict__ out)
{
    __shared__ float qh [64][36], qrh[64][36];   // row-block q, one d-half
    __shared__ float kh [32][36], krh[32][36];   // m-tile k, one d-half
    __shared__ float sP [64 * 33];               // P tile [64][33]; reused as Sc [32][64]
    __shared__ float svb[32 * 68];               // v tile [32][68]; reused as Scr [32][64]
    __shared__ float kc[64], krc[64];

    const int t = threadIdx.x;
    const int blk = blockIdx.x;
    const int chunk = blk >> 1;
    const int rb = blk & 1;
    const int bh = chunk >> 6;
    const int c  = chunk & 63;
    const size_t gbase   = (size_t)bh * N_ * D_ + (size_t)c * C_ * D_;
    const size_t rowbase = gbase + (size_t)rb * 64 * D_;
    const float* st = ws + (size_t)chunk * STATE;
    const int nt = rb ? 4 : 2;             // m-tiles needed (causal)

    // pass-1 mapping: rows (r, r+32), cols mj..mj+3
    const int r  = t >> 3;                 // 0..31
    const int mj = (t & 7) * 4;            // 0..28
    // pass-2 / carry / output mapping: row n, 16 e's
    const int n  = t >> 2;                 // 0..63
    const int e0 = (t & 3) * 16;

    float p[4][2][4];
#pragma unroll
    for (int a = 0; a < 4; ++a)
#pragma unroll
        for (int b = 0; b < 2; ++b)
#pragma unroll
            for (int j = 0; j < 4; ++j) p[a][b][j] = 0.f;
    float acc[16];
#pragma unroll
    for (int j = 0; j < 16; ++j) acc[j] = 0.f;
    float den = 0.f;

    if (t < 128) {                          // carry vectors
        if (t < 64) kc[t] = st[t];
        else        krc[t - 64] = st[t];
    }

    // ---- accumulate P over two d-halves ----
    for (int dh = 0; dh < 2; ++dh) {
        __syncthreads();                    // qh safe to overwrite
#pragma unroll
        for (int i = 0; i < 2; ++i) {       // 64x32 floats each
            int fi = i * 256 + t;
            int row = fi >> 3, c4 = (fi & 7) * 4;
            const size_t g = rowbase + (size_t)row * D_ + dh * 32 + c4;
            *(float4*)&qh [row][c4] = *(const float4*)(gq  + g);
            *(float4*)&qrh[row][c4] = *(const float4*)(gqr + g);
        }
#pragma unroll
        for (int mt = 0; mt < 4; ++mt) {
            if (mt >= nt) continue;
            __syncthreads();                // kh safe to overwrite; qh visible (first mt)
            {
                int row = t >> 3, c4 = (t & 7) * 4;   // 32x32 floats
                const size_t g = gbase + (size_t)(mt * 32 + row) * D_ + dh * 32 + c4;
                *(float4*)&kh [row][c4] = *(const float4*)(gk  + g);
                *(float4*)&krh[row][c4] = *(const float4*)(gkr + g);
            }
            __syncthreads();
#pragma unroll
            for (int dv = 0; dv < 8; ++dv) {
                const float4 qa  = *(const float4*)&qh [r]     [dv * 4];
                const float4 qb  = *(const float4*)&qh [r + 32][dv * 4];
                const float4 qra = *(const float4*)&qrh[r]     [dv * 4];
                const float4 qrb = *(const float4*)&qrh[r + 32][dv * 4];
#pragma unroll
                for (int j = 0; j < 4; ++j) {
                    const float4 kv  = *(const float4*)&kh [mj + j][dv * 4];
                    const float4 krv = *(const float4*)&krh[mj + j][dv * 4];
                    p[mt][0][j] += qa.x * kv.x + qa.y * kv.y + qa.z * kv.z + qa.w * kv.w
                                 + qra.x * krv.x + qra.y * krv.y + qra.z * krv.z + qra.w * krv.w;
                    p[mt][1][j] += qb.x * kv.x + qb.y * kv.y + qb.z * kv.z + qb.w * kv.w
                                 + qrb.x * krv.x + qrb.y * krv.y + qrb.z * krv.z + qrb.w * krv.w;
                }
            }
        }
    }

    // ---- pass 2: masked P -> LDS, out += P*V, den += rowsum(P) ----
#pragma unroll
    for (int mt = 0; mt < 4; ++mt) {
        if (mt >= nt) continue;
        __syncthreads();                    // sP/svb safe to overwrite
#pragma unroll
        for (int j = 0; j < 4; ++j) {
            const int m_in_chunk = mt * 32 + mj + j;
            const int row0 = rb * 64 + r;
            const int row1 = rb * 64 + r + 32;
            sP[r * 33 + mj + j]        = (m_in_chunk <= row0) ? p[mt][0][j] : 0.f;
            sP[(r + 32) * 33 + mj + j] = (m_in_chunk <= row1) ? p[mt][1][j] : 0.f;
        }
#pragma unroll
        for (int i = 0; i < 2; ++i) {       // v tile 32x64
            int fi = i * 256 + t;
            int row = fi >> 4, c4 = (fi & 15) * 4;
            *(float4*)&svb[row * 68 + c4] =
                *(const float4*)(gv + gbase + (size_t)(mt * 32 + row) * D_ + c4);
        }
        __syncthreads();
#pragma unroll 4
        for (int m = 0; m < 32; ++m) {
            const float pv = sP[n * 33 + m];
            den += pv;
            float4 vv0 = *(const float4*)&svb[m * 68 + e0];
            float4 vv1 = *(const float4*)&svb[m * 68 + e0 + 4];
            float4 vv2 = *(const float4*)&svb[m * 68 + e0 + 8];
            float4 vv3 = *(const float4*)&svb[m * 68 + e0 + 12];
            acc[0]  += pv * vv0.x; acc[1]  += pv * vv0.y; acc[2]  += pv * vv0.z; acc[3]  += pv * vv0.w;
            acc[4]  += pv * vv1.x; acc[5]  += pv * vv1.y; acc[6]  += pv * vv1.z; acc[7]  += pv * vv1.w;
            acc[8]  += pv * vv2.x; acc[9]  += pv * vv2.y; acc[10] += pv * vv2.z; acc[11] += pv * vv2.w;
            acc[12] += pv * vv3.x; acc[13] += pv * vv3.y; acc[14] += pv * vv3.z; acc[15] += pv * vv3.w;
        }
    }

    // ---- carry pass: out += Q*Sc + Qr*Scr, den += q.kc + qr.krc ----
    for (int dh = 0; dh < 2; ++dh) {
        __syncthreads();                    // qh, sP, svb safe to overwrite
#pragma unroll
        for (int i = 0; i < 2; ++i) {
            int fi = i * 256 + t;
            int row = fi >> 3, c4 = (fi & 7) * 4;
            const size_t g = rowbase + (size_t)row * D_ + dh * 32 + c4;
            *(float4*)&qh [row][c4] = *(const float4*)(gq  + g);
            *(float4*)&qrh[row][c4] = *(const float4*)(gqr + g);
        }
#pragma unroll
        for (int i = 0; i < 2; ++i) {       // Sc/Scr halves: 32x64 each, stored flat
            int fi = i * 256 + t;
            int row = fi >> 4, c4 = (fi & 15) * 4;
            *(float4*)&sP [row * 64 + c4] = *(const float4*)(st + 128        + (size_t)(dh * 32 + row) * 64 + c4);
            *(float4*)&svb[row * 64 + c4] = *(const float4*)(st + 128 + 4096 + (size_t)(dh * 32 + row) * 64 + c4);
        }
        __syncthreads();
#pragma unroll 4
        for (int d = 0; d < 32; ++d) {
            const float qv  = qh [n][d];
            const float qrv = qrh[n][d];
            den += qv * kc[dh * 32 + d] + qrv * krc[dh * 32 + d];
#pragma unroll
            for (int g = 0; g < 4; ++g) {
                const float4 s  = *(const float4*)&sP [d * 64 + e0 + g * 4];
                const float4 sr = *(const float4*)&svb[d * 64 + e0 + g * 4];
                acc[g * 4 + 0] += qv * s.x + qrv * sr.x;
                acc[g * 4 + 1] += qv * s.y + qrv * sr.y;
                acc[g * 4 + 2] += qv * s.z + qrv * sr.z;
                acc[g * 4 + 3] += qv * s.w + qrv * sr.w;
            }
        }
    }

    const float dinv = 1.0f / (den + EPS_);
    const size_t ob = (size_t)bh * N_ * E_ + (size_t)(c * C_ + rb * 64 + n) * E_ + e0;
    *(float4*)(out + ob)      = make_float4(acc[0] * dinv,  acc[1] * dinv,  acc[2] * dinv,  acc[3] * dinv);
    *(float4*)(out + ob + 4)  = make_float4(acc[4] * dinv,  acc[5] * dinv,  acc[6] * dinv,  acc[7] * dinv);
    *(float4*)(out + ob + 8)  = make_float4(acc[8] * dinv,  acc[9] * dinv,  acc[10] * dinv, acc[11] * dinv);
    *(float4*)(out + ob + 12) = make_float4(acc[12] * dinv, acc[13] * dinv, acc[14] * dinv, acc[15] * dinv);
}

extern "C" void kernel_launch(void* const* d_in, const int* in_sizes, int n_in,
                              void* d_out, int out_size, void* d_ws, size_t ws_size,
                              hipStream_t stream) {
    const float* q  = (const float*)d_in[0];
    const float* k  = (const float*)d_in[1];
    const float* qr = (const float*)d_in[2];
    const float* kr = (const float*)d_in[3];
    const float* v  = (const float*)d_in[4];
    float* out = (float*)d_out;
    float* ws  = (float*)d_ws;

    chunk_states<<<NCHUNKS, 256, 0, stream>>>(k, kr, v, ws);
    scan_states<<<dim3(BH, 33), 256, 0, stream>>>(ws, out);
    chunk_out<<<NCHUNKS * 2, 256, 0, stream>>>(q, qr, k, kr, v, ws, out);
}

// Round 2
// 401.047 us; speedup vs baseline: 6.0275x; 6.0275x over previous
//
#include <hip/hip_runtime.h>

// Chunked causal linear attention. B=4 H=8 N=8192 D=E=64 C=128.
//  1) chunk_states (f32): per-chunk totals {sumK, sumKr, K^T V, Kr^T V} -> ws
//  2) scan_states  (f32): exclusive prefix over 64 chunks per (b,h); totals -> d_out tail
//  3) chunk_out   (bf16 MFMA): P = tril(QK^T + QrKr^T);
//       out = (P V + Q Sc + Qr Scr) / (rowsum(P) + q.kc + qr.krc + eps)
// ws requirement: 2048 * 8320 * 4 = 68,157,440 bytes.

typedef short bf16x8 __attribute__((ext_vector_type(8)));
typedef float f32x4  __attribute__((ext_vector_type(4)));

constexpr int B_ = 4, H_ = 8, BH = 32;
constexpr int N_ = 8192, D_ = 64, E_ = 64, C_ = 128;
constexpr int NC = 64;
constexpr int NCHUNKS = BH * NC;     // 2048
constexpr int STATE = 64 + 64 + 64 * 64 + 64 * 64;  // 8320 floats
#define EPS_ 1e-6f

constexpr size_t OUT_ELEMS = (size_t)BH * N_ * E_;
constexpr size_t ZOFF  = OUT_ELEMS;
constexpr size_t SOFF  = ZOFF  + (size_t)BH * 64;
constexpr size_t ZROFF = SOFF  + (size_t)BH * 4096;
constexpr size_t SROFF = ZROFF + (size_t)BH * 64;

// ---- bf16 pack helpers (RNE) ----
__device__ inline unsigned cvt2(float a, float b){
    union { float f; unsigned u; } x, y; x.f = a; y.f = b;
    unsigned lo = (x.u + 0x7fffu + ((x.u >> 16) & 1u)) >> 16;
    unsigned hi = (y.u + 0x7fffu + ((y.u >> 16) & 1u)) >> 16;
    return lo | (hi << 16);
}
__device__ inline unsigned short cvt1(float a){
    union { float f; unsigned u; } x; x.f = a;
    return (unsigned short)((x.u + 0x7fffu + ((x.u >> 16) & 1u)) >> 16);
}

// ---------------- Phase 1: per-chunk state totals (f32, unchanged) ----------------
__global__ __launch_bounds__(256) void chunk_states(
    const float* __restrict__ gk, const float* __restrict__ gkr,
    const float* __restrict__ gv, float* __restrict__ ws)
{
    __shared__ float sk[32][68], skr[32][68], sv[32][68];
    const int t = threadIdx.x;
    const int cid = blockIdx.x;
    const int bh = cid >> 6;
    const int c  = cid & 63;
    const size_t gbase = (size_t)bh * N_ * D_ + (size_t)c * C_ * D_;

    const int d2 = t >> 3;
    const int e0 = (t & 7) * 8;

    float acc0[8], acc1[8], accr0[8], accr1[8];
#pragma unroll
    for (int j = 0; j < 8; ++j) { acc0[j]=0.f; acc1[j]=0.f; accr0[j]=0.f; accr1[j]=0.f; }
    float sumk = 0.f;

    for (int mt = 0; mt < 4; ++mt) {
        const int m0 = mt * 32;
#pragma unroll
        for (int i = 0; i < 2; ++i) {
            int fi = i * 256 + t;
            int row = fi >> 4, c4 = (fi & 15) * 4;
            const size_t g = gbase + (size_t)(m0 + row) * D_ + c4;
            *(float4*)&sk [row][c4] = *(const float4*)(gk  + g);
            *(float4*)&skr[row][c4] = *(const float4*)(gkr + g);
            *(float4*)&sv [row][c4] = *(const float4*)(gv  + g);
        }
        __syncthreads();
#pragma unroll 4
        for (int m = 0; m < 32; ++m) {
            const float kd0  = sk [m][d2], kd1  = sk [m][d2 + 32];
            const float krd0 = skr[m][d2], krd1 = skr[m][d2 + 32];
            const float4 va = *(const float4*)&sv[m][e0];
            const float4 vb = *(const float4*)&sv[m][e0 + 4];
            const float vv[8] = {va.x,va.y,va.z,va.w, vb.x,vb.y,vb.z,vb.w};
#pragma unroll
            for (int j = 0; j < 8; ++j) {
                acc0 [j] += kd0  * vv[j];
                acc1 [j] += kd1  * vv[j];
                accr0[j] += krd0 * vv[j];
                accr1[j] += krd1 * vv[j];
            }
        }
        if (t < 64) {
            for (int m = 0; m < 32; ++m) sumk += sk[m][t];
        } else if (t < 128) {
            const int d = t - 64;
            for (int m = 0; m < 32; ++m) sumk += skr[m][d];
        }
        __syncthreads();
    }

    float* st = ws + (size_t)cid * STATE;
    if (t < 128) st[t] = sumk;
    float* cs  = st + 128;
    float* csr = st + 128 + 64 * 64;
    *(float4*)&cs [d2 * 64 + e0]            = make_float4(acc0[0], acc0[1], acc0[2], acc0[3]);
    *(float4*)&cs [d2 * 64 + e0 + 4]        = make_float4(acc0[4], acc0[5], acc0[6], acc0[7]);
    *(float4*)&cs [(d2 + 32) * 64 + e0]     = make_float4(acc1[0], acc1[1], acc1[2], acc1[3]);
    *(float4*)&cs [(d2 + 32) * 64 + e0 + 4] = make_float4(acc1[4], acc1[5], acc1[6], acc1[7]);
    *(float4*)&csr[d2 * 64 + e0]            = make_float4(accr0[0], accr0[1], accr0[2], accr0[3]);
    *(float4*)&csr[d2 * 64 + e0 + 4]        = make_float4(accr0[4], accr0[5], accr0[6], accr0[7]);
    *(float4*)&csr[(d2 + 32) * 64 + e0]     = make_float4(accr1[0], accr1[1], accr1[2], accr1[3]);
    *(float4*)&csr[(d2 + 32) * 64 + e0 + 4] = make_float4(accr1[4], accr1[5], accr1[6], accr1[7]);
}

// ---------------- Phase 2: exclusive scan (unchanged) ----------------
__global__ __launch_bounds__(256) void scan_states(float* __restrict__ ws, float* __restrict__ out)
{
    const int bh = blockIdx.x;
    const int j  = blockIdx.y * 256 + threadIdx.x;
    if (j >= STATE) return;
    float run = 0.f;
    const size_t base = (size_t)bh * NC * STATE + j;
#pragma unroll 4
    for (int c = 0; c < NC; ++c) {
        const size_t idx = base + (size_t)c * STATE;
        const float x = ws[idx];
        ws[idx] = run;
        run += x;
    }
    if (j < 64)        out[ZOFF  + (size_t)bh * 64   + j]          = run;
    else if (j < 128)  out[ZROFF + (size_t)bh * 64   + (j - 64)]   = run;
    else if (j < 4224) out[SOFF  + (size_t)bh * 4096 + (j - 128)]  = run;
    else               out[SROFF + (size_t)bh * 4096 + (j - 4224)] = run;
}

// ---------------- Phase 3: MFMA chunk output ----------------
// LDS frag-major layout. Tile = 64 lanes x 8 bf16 (one 16x32 MFMA operand), padded to 520 u16.
// Assumed (consistent A/B) frag map: lane = (row_or_col & 15) + 16*((k&31)>>3), slot = k&7.
// C/D (verified m89): col = lane&15, row = 4*(lane>>4) + reg.
constexpr int TILE = 520;
constexpr int SQ0  = 0;                    // A-frags Q,Qr: ((ten*4+tr)*2+td)  -> 16 tiles
constexpr int SK0  = 8320;                 // B-frags K,Kr: ((ten*2+td)*4+tm)  -> 16 tiles
constexpr int SV0  = 16640;                // B-frags V   : (tkm*4+te)         -> 8 tiles
constexpr int SSC0 = 8320;                 // B-frags Sc,Scr (+aug te=4): (ten*10+td*5+te) -> 20 tiles (aliases SK0/SV0)
constexpr int SP0  = 20800;                // A-frags masked P: (w*2+tk)       -> 8 tiles
constexpr int SM_TOT = 24960;              // 49,920 bytes

#define MFMA(A,B,C) __builtin_amdgcn_mfma_f32_16x16x32_bf16((A),(B),(C),0,0,0)

// stage one row-major 64x64 f32 matrix into frag-major bf16 tiles.
// element (r,c): tile = (r>>4)*mr + (c>>5)*mc ; lane = (r&15)+16*((c&31)>>3) ; slot = c&7
__device__ inline void stage_row(const float* p, unsigned short* dst, int r, int c0, int mr, int mc){
    float4 f0 = ((const float4*)p)[0], f1 = ((const float4*)p)[1];
    float4 f2 = ((const float4*)p)[2], f3 = ((const float4*)p)[3];
    int tile = (r >> 4) * mr + (c0 >> 5) * mc;
    int g0   = (c0 & 31) >> 3;
    uint4 u0 = make_uint4(cvt2(f0.x,f0.y), cvt2(f0.z,f0.w), cvt2(f1.x,f1.y), cvt2(f1.z,f1.w));
    uint4 u1 = make_uint4(cvt2(f2.x,f2.y), cvt2(f2.z,f2.w), cvt2(f3.x,f3.y), cvt2(f3.z,f3.w));
    *(uint4*)&dst[tile*TILE + ((r&15) + 16* g0   )*8] = u0;
    *(uint4*)&dst[tile*TILE + ((r&15) + 16*(g0+1))*8] = u1;
}

// stage a 64x64 f32 [k-dim rows][cols] matrix where the k-dim is the SOURCE ROW:
// element (rr,col): tile = (rr>>5)*mr + (col>>4)*mc ; lane = (col&15)+16*((rr&31)>>3) ; slot = rr&7
__device__ inline void stage_colT(const float* src, int ldr, unsigned short* dst, int mr, int mc){
    const int t = threadIdx.x;
    const int col = t & 63, r0 = (t >> 6) * 16;
    float v[16];
#pragma unroll
    for (int i = 0; i < 16; ++i) v[i] = src[(size_t)(r0 + i) * ldr + col];
#pragma unroll
    for (int h = 0; h < 2; ++h) {
        int rr = r0 + 8 * h;
        int tile = (rr >> 5) * mr + (col >> 4) * mc;
        uint4 u = make_uint4(cvt2(v[8*h+0],v[8*h+1]), cvt2(v[8*h+2],v[8*h+3]),
                             cvt2(v[8*h+4],v[8*h+5]), cvt2(v[8*h+6],v[8*h+7]));
        *(uint4*)&dst[tile*TILE + ((col&15) + 16*((rr&31)>>3))*8] = u;
    }
}

__global__ __launch_bounds__(256, 3) void chunk_out(
    const float* __restrict__ gq, const float* __restrict__ gqr,
    const float* __restrict__ gk, const float* __restrict__ gkr,
    const float* __restrict__ gv, const float* __restrict__ ws,
    float* __restrict__ out)
{
    __shared__ unsigned short sm[SM_TOT];
    const int t = threadIdx.x;
    const int blk = blockIdx.x, chunk = blk >> 1, rb = blk & 1;
    const int bh = chunk >> 6, c = chunk & 63;
    const size_t gbase = (size_t)bh * N_ * D_ + (size_t)c * C_ * D_;
    const float* st = ws + (size_t)chunk * STATE;
    const int w = t >> 6, lane = t & 63, lg = lane >> 4, lm = lane & 15;

    // ---- stage Q, Qr as A-frags ----
    {
        const int r = t >> 2, c0 = (t & 3) * 16;
        const size_t g = gbase + (size_t)rb * 64 * D_ + (size_t)r * D_ + c0;
        stage_row(gq  + g, sm + SQ0,            r, c0, 2, 1);
        stage_row(gqr + g, sm + SQ0 + 8 * TILE, r, c0, 2, 1);
    }

    f32x4 oacc[4];
#pragma unroll
    for (int te = 0; te < 4; ++te) oacc[te] = f32x4{0.f, 0.f, 0.f, 0.f};
    f32x4 acc4 = f32x4{0.f, 0.f, 0.f, 0.f};
    float denp[4] = {0.f, 0.f, 0.f, 0.f};
    bf16x8 qf[2][2];

    const int TMmax = rb * 4 + w;                 // last m-tile (16) this wave needs
    const int TKtop = ((TMmax >> 1) << 1) + 1;    // last m-tile covered by PV 32-wide reads

#define KFRG(ten,td,tm)  (*(const bf16x8*)&sm[SK0  + (((ten)*2+(td))*4+(tm))*TILE + lane*8])
#define VFRG(tk,te)      (*(const bf16x8*)&sm[SV0  + ((tk)*4+(te))*TILE + lane*8])
#define SCFRG(ten,td,te) (*(const bf16x8*)&sm[SSC0 + ((ten)*10+(td)*5+(te))*TILE + lane*8])

    for (int mh = 0; mh < 2; ++mh) {
        __syncthreads();                          // prev-half reads done; Q visible after first
        if (mh == 0 || rb == 1) {
            const int r = t >> 2, c0 = (t & 3) * 16;
            const size_t kg = gbase + (size_t)mh * 64 * D_ + (size_t)r * D_ + c0;
            stage_row(gk  + kg, sm + SK0,            r, c0, 1, 4);
            stage_row(gkr + kg, sm + SK0 + 8 * TILE, r, c0, 1, 4);
            stage_colT(gv + gbase + (size_t)mh * 64 * D_, D_, sm + SV0, 4, 1);
        }
        __syncthreads();
        if (mh == 0) {
#pragma unroll
            for (int td = 0; td < 2; ++td) {
                qf[0][td] = *(const bf16x8*)&sm[SQ0 +            (w*2+td)*TILE + lane*8];
                qf[1][td] = *(const bf16x8*)&sm[SQ0 + 8*TILE +   (w*2+td)*TILE + lane*8];
            }
        }
        if (mh == 0 || rb == 1) {
            // ---- P tiles: compute, mask, rowsum, restage as PV A-frags ----
#pragma unroll
            for (int tm = 0; tm < 4; ++tm) {
                const int TM = mh * 4 + tm;
                if (TM <= TKtop) {
                    f32x4 a = f32x4{0.f, 0.f, 0.f, 0.f};
                    if (TM <= TMmax) {
                        a = MFMA(qf[0][0], KFRG(0,0,tm), a);
                        a = MFMA(qf[0][1], KFRG(0,1,tm), a);
                        a = MFMA(qf[1][0], KFRG(1,0,tm), a);
                        a = MFMA(qf[1][1], KFRG(1,1,tm), a);
                    }
                    const int mb = TM * 16 + lm;
                    const int pb = SP0 + (w*2 + (tm>>1))*TILE
                                 + 16*((tm&1)*2 + (lm>>3))*8 + (lm&7);
#pragma unroll
                    for (int r = 0; r < 4; ++r) {
                        const int ng = rb*64 + w*16 + lg*4 + r;
                        const float pv = (TM <= TMmax && mb <= ng) ? a[r] : 0.f;
                        denp[r] += pv;
                        sm[pb + (lg*4 + r)*8] = cvt1(pv);
                    }
                }
            }
            // ---- PV: out += P_half * V_half ----
#pragma unroll
            for (int tk = 0; tk < 2; ++tk) {
                const int TK = mh * 2 + tk;
                if (TK <= (TMmax >> 1)) {
                    bf16x8 pa = *(const bf16x8*)&sm[SP0 + (w*2+tk)*TILE + lane*8];
#pragma unroll
                    for (int te = 0; te < 4; ++te)
                        oacc[te] = MFMA(pa, VFRG(tk,te), oacc[te]);
                }
            }
        }
    }

    // ---- carry: stage Sc/Scr (+aug col with kc/krc), GEMM ----
    __syncthreads();                               // PV reads of SK0/SV0 done
    stage_colT(st + 128,        64, sm + SSC0,             5, 1);
    stage_colT(st + 128 + 4096, 64, sm + SSC0 + 10 * TILE, 5, 1);
    for (int i = t; i < 4 * 260; i += 256) {       // zero the 4 aug tiles
        int tile = i / 260, off = i % 260;
        int ten = tile >> 1, td = tile & 1;
        *(unsigned*)&sm[SSC0 + (ten*10 + td*5 + 4)*TILE + off*2] = 0u;
    }
    __syncthreads();
    if (t < 128) {                                 // aug col0: kc (ten=0) / krc (ten=1)
        int ten = t >> 6, d = t & 63;
        sm[SSC0 + (ten*10 + (d>>5)*5 + 4)*TILE + (16*((d&31)>>3))*8 + (d&7)] = cvt1(st[t]);
    }
    __syncthreads();
#pragma unroll
    for (int td = 0; td < 2; ++td) {
#pragma unroll
        for (int te = 0; te < 4; ++te) {
            oacc[te] = MFMA(qf[0][td], SCFRG(0,td,te), oacc[te]);
            oacc[te] = MFMA(qf[1][td], SCFRG(1,td,te), oacc[te]);
        }
        acc4 = MFMA(qf[0][td], SCFRG(0,td,4), acc4);
        acc4 = MFMA(qf[1][td], SCFRG(1,td,4), acc4);
    }

    // ---- denominator, scale, store ----
    const size_t orow = (size_t)bh * N_ * E_ + (size_t)(c * C_ + rb * 64 + w * 16) * E_;
#pragma unroll
    for (int r = 0; r < 4; ++r) {
        float d = denp[r];
        d += __shfl_xor(d, 1); d += __shfl_xor(d, 2);
        d += __shfl_xor(d, 4); d += __shfl_xor(d, 8);
        const float dc = __shfl(acc4[r], lane & 48);
        const float dinv = 1.0f / (d + dc + EPS_);
        const size_t ob = orow + (size_t)(lg * 4 + r) * E_ + lm;
        out[ob +  0] = oacc[0][r] * dinv;
        out[ob + 16] = oacc[1][r] * dinv;
        out[ob + 32] = oacc[2][r] * dinv;
        out[ob + 48] = oacc[3][r] * dinv;
    }
#undef KFRG
#undef VFRG
#undef SCFRG
}

extern "C" void kernel_launch(void* const* d_in, const int* in_sizes, int n_in,
                              void* d_out, int out_size, void* d_ws, size_t ws_size,
                              hipStream_t stream) {
    const float* q  = (const float*)d_in[0];
    const float* k  = (const float*)d_in[1];
    const float* qr = (const float*)d_in[2];
    const float* kr = (const float*)d_in[3];
    const float* v  = (const float*)d_in[4];
    float* out = (float*)d_out;
    float* ws  = (float*)d_ws;

    chunk_states<<<NCHUNKS, 256, 0, stream>>>(k, kr, v, ws);
    scan_states<<<dim3(BH, 33), 256, 0, stream>>>(ws, out);
    chunk_out<<<NCHUNKS * 2, 256, 0, stream>>>(q, qr, k, kr, v, ws, out);
}

// Round 3
// 398.382 us; speedup vs baseline: 6.0678x; 1.0067x over previous
//
#include <hip/hip_runtime.h>

// Chunked causal linear attention. B=4 H=8 N=8192 D=E=64 C=128.
//  1) chunk_states (bf16 MFMA, hi/lo split): per-chunk {sumK, sumKr, K^T V, Kr^T V} -> ws (f32)
//  2) scan_states  (f32, float4): exclusive prefix over 64 chunks per (b,h); totals -> d_out tail
//  3) chunk_out    (bf16 MFMA): P = tril(QK^T + QrKr^T);
//       out = (P V + Q Sc + Qr Scr) / (rowsum(P) + q.kc + qr.krc + eps)
// ws requirement: 2048 * 8320 * 4 = 68,157,440 bytes.

typedef short bf16x8 __attribute__((ext_vector_type(8)));
typedef float f32x4  __attribute__((ext_vector_type(4)));
union U16x8 { bf16x8 v; uint4 u; };

constexpr int BH = 32;
constexpr int N_ = 8192, D_ = 64, E_ = 64, C_ = 128;
constexpr int NC = 64;
constexpr int NCHUNKS = BH * NC;     // 2048
constexpr int STATE = 8320;          // 64+64+4096+4096 floats per chunk-state
#define EPS_ 1e-6f

constexpr size_t OUT_ELEMS = (size_t)BH * N_ * E_;
constexpr size_t ZOFF  = OUT_ELEMS;
constexpr size_t SOFF  = ZOFF  + (size_t)BH * 64;
constexpr size_t ZROFF = SOFF  + (size_t)BH * 4096;
constexpr size_t SROFF = ZROFF + (size_t)BH * 64;

// ---- bf16 helpers (RNE) ----
__device__ inline unsigned cvt2(float a, float b){
    union { float f; unsigned u; } x, y; x.f = a; y.f = b;
    unsigned lo = (x.u + 0x7fffu + ((x.u >> 16) & 1u)) >> 16;
    unsigned hi = (y.u + 0x7fffu + ((y.u >> 16) & 1u)) >> 16;
    return lo | (hi << 16);
}
__device__ inline unsigned short cvt1(float a){
    union { float f; unsigned u; } x; x.f = a;
    return (unsigned short)((x.u + 0x7fffu + ((x.u >> 16) & 1u)) >> 16);
}
__device__ inline float bflo(float x, unsigned short hi){
    union { unsigned u; float f; } h; h.u = ((unsigned)hi) << 16;
    return x - h.f;
}

constexpr int TILE = 520;            // one 16x32 MFMA operand tile (512 bf16 + pad)
#define MFMA(A,B,C) __builtin_amdgcn_mfma_f32_16x16x32_bf16((A),(B),(C),0,0,0)

// ---------------- Phase 1: per-chunk state totals (MFMA hi/lo) ----------------
// A-frags: K^T, Kr^T (hi+lo); B-frags: V (hi+lo), ones-column (exact).
// S = Ah*Bh + Al*Bh + Ah*Bl ; sums = (Ah+Al)*ones. f32 accum, f32 out to ws.
constexpr int AKH = 0, AKL = 8, ARH = 16, ARL = 24, BVH = 32, BVL = 40, BON = 48;
constexpr int SM1_TOT = 50 * TILE;   // 52,000 B

__global__ __launch_bounds__(256, 3) void chunk_states(
    const float* __restrict__ gk, const float* __restrict__ gkr,
    const float* __restrict__ gv, float* __restrict__ ws)
{
    __shared__ unsigned short sm[SM1_TOT];
    const int t = threadIdx.x;
    const int cid = blockIdx.x, bh = cid >> 6, c = cid & 63;
    const size_t gbase = (size_t)bh * N_ * D_ + (size_t)c * C_ * D_;
    const int w = t >> 6, lane = t & 63, lg = lane >> 4, lm = lane & 15;
    const int col = t & 63, r0g = (t >> 6) * 16;

    float kv[16], krv[16], vv[16];
    auto load_half = [&](int h){
        const size_t base = gbase + (size_t)(h * 64 + r0g) * D_ + col;
#pragma unroll
        for (int i = 0; i < 16; ++i) {
            kv [i] = gk [base + (size_t)i * D_];
            krv[i] = gkr[base + (size_t)i * D_];
            vv [i] = gv [base + (size_t)i * D_];
        }
    };
    // pack one 16-row strip into hi/lo frag tiles (k-dim = source row)
    auto write_hl = [&](const float* v16, int hiT, int loT){
#pragma unroll
        for (int hh = 0; hh < 2; ++hh) {
            const int rr = r0g + 8 * hh;
            const int tile = (rr >> 5) * 4 + (col >> 4);
            const int off = ((col & 15) + 16 * ((rr & 31) >> 3)) * 8;
            unsigned short h8[8]; float l8[8];
#pragma unroll
            for (int j = 0; j < 8; ++j) {
                h8[j] = cvt1(v16[8*hh + j]);
                l8[j] = bflo(v16[8*hh + j], h8[j]);
            }
            uint4 uh = make_uint4((unsigned)h8[0] | ((unsigned)h8[1] << 16),
                                  (unsigned)h8[2] | ((unsigned)h8[3] << 16),
                                  (unsigned)h8[4] | ((unsigned)h8[5] << 16),
                                  (unsigned)h8[6] | ((unsigned)h8[7] << 16));
            uint4 ul = make_uint4(cvt2(l8[0],l8[1]), cvt2(l8[2],l8[3]),
                                  cvt2(l8[4],l8[5]), cvt2(l8[6],l8[7]));
            *(uint4*)&sm[(hiT + tile) * TILE + off] = uh;
            *(uint4*)&sm[(loT + tile) * TILE + off] = ul;
        }
    };

    // ones-column B tiles (col 0 = 1.0)
    for (int i = t; i < 2 * TILE; i += 256) {
        const int tile = i / TILE, off = i % TILE;
        unsigned short val = (off < 512 && ((off >> 3) & 15) == 0) ? (unsigned short)0x3F80 : (unsigned short)0;
        sm[(BON + tile) * TILE + off] = val;
    }

    f32x4 aK[4], aR[4], sK = {0.f,0.f,0.f,0.f}, sR = {0.f,0.f,0.f,0.f};
#pragma unroll
    for (int e = 0; e < 4; ++e) { aK[e] = f32x4{0.f,0.f,0.f,0.f}; aR[e] = f32x4{0.f,0.f,0.f,0.f}; }

    auto FR = [&](int tile)->bf16x8 { return *(const bf16x8*)&sm[tile * TILE + lane * 8]; };
    auto compute = [&](){
#pragma unroll
        for (int kt = 0; kt < 2; ++kt) {
            bf16x8 ah = FR(AKH + kt*4 + w), al = FR(AKL + kt*4 + w);
            bf16x8 rh = FR(ARH + kt*4 + w), rl = FR(ARL + kt*4 + w);
            bf16x8 bo = FR(BON + kt);
            sK = MFMA(ah, bo, sK); sK = MFMA(al, bo, sK);
            sR = MFMA(rh, bo, sR); sR = MFMA(rl, bo, sR);
#pragma unroll
            for (int et = 0; et < 4; ++et) {
                bf16x8 bh = FR(BVH + kt*4 + et), bl = FR(BVL + kt*4 + et);
                aK[et] = MFMA(ah, bh, aK[et]);
                aK[et] = MFMA(al, bh, aK[et]);
                aK[et] = MFMA(ah, bl, aK[et]);
                aR[et] = MFMA(rh, bh, aR[et]);
                aR[et] = MFMA(rl, bh, aR[et]);
                aR[et] = MFMA(rh, bl, aR[et]);
            }
        }
    };

    load_half(0);
    write_hl(kv, AKH, AKL); write_hl(krv, ARH, ARL); write_hl(vv, BVH, BVL);
    load_half(1);                       // prefetch into regs while half-0 computes
    __syncthreads();
    compute();
    __syncthreads();
    write_hl(kv, AKH, AKL); write_hl(krv, ARH, ARL); write_hl(vv, BVH, BVL);
    __syncthreads();
    compute();

    float* st = ws + (size_t)cid * STATE;
    if (lm == 0) {
#pragma unroll
        for (int r = 0; r < 4; ++r) {
            const int d = w*16 + lg*4 + r;
            st[d]      = sK[r];
            st[64 + d] = sR[r];
        }
    }
    float* cs  = st + 128;
    float* csr = st + 128 + 4096;
#pragma unroll
    for (int et = 0; et < 4; ++et)
#pragma unroll
        for (int r = 0; r < 4; ++r) {
            const int d = w*16 + lg*4 + r, e = et*16 + lm;
            cs [d*64 + e] = aK[et][r];
            csr[d*64 + e] = aR[et][r];
        }
}

// ---------------- Phase 2: exclusive scan, float4 ----------------
__global__ __launch_bounds__(256) void scan_states(float* __restrict__ ws, float* __restrict__ out)
{
    const int bh = blockIdx.x;
    const int j4 = blockIdx.y * 256 + threadIdx.x;
    if (j4 >= STATE / 4) return;        // 2080
    float4 run = make_float4(0.f, 0.f, 0.f, 0.f);
    float* base = ws + (size_t)bh * NC * STATE + (size_t)j4 * 4;
#pragma unroll 8
    for (int c = 0; c < NC; ++c) {
        float4 x = *(float4*)(base + (size_t)c * STATE);
        *(float4*)(base + (size_t)c * STATE) = run;
        run.x += x.x; run.y += x.y; run.z += x.z; run.w += x.w;
    }
    const int j = j4 * 4;
    float* dst;
    if (j < 64)        dst = out + ZOFF  + (size_t)bh*64   + j;
    else if (j < 128)  dst = out + ZROFF + (size_t)bh*64   + (j - 64);
    else if (j < 4224) dst = out + SOFF  + (size_t)bh*4096 + (j - 128);
    else               dst = out + SROFF + (size_t)bh*4096 + (j - 4224);
    *(float4*)dst = run;
}

// ---------------- Phase 3: MFMA chunk output ----------------
// LDS tiles: SK0=0 (K,Kr B-frags, 16), SV0=16 (V B-frags, 8), SP0=24 (P A-frags, 8).
// SSC0 aliases 0..19 for the carry stage. Q/Qr live in registers (direct global load).
constexpr int SK0 = 0, SV0 = 16, SP0 = 24, SSC0 = 0;
constexpr int SM3_TOT = 32 * TILE;     // 33,280 B

#define KFRG(ten,td,tm)  (*(const bf16x8*)&sm[(SK0 + ((ten)*2+(td))*4+(tm))*TILE + lane*8])
#define VFRG(tk,te)      (*(const bf16x8*)&sm[(SV0 + (tk)*4+(te))*TILE + lane*8])
#define SCFRG(ten,td,te) (*(const bf16x8*)&sm[(SSC0 + (ten)*10+(td)*5+(te))*TILE + lane*8])

// stage a 64-row x 64-col f32 (k-dim = row) into bf16 B-frag tiles
__device__ inline void stage_colT(const float* src, int ldr, unsigned short* dst, int mr, int mc){
    const int t = threadIdx.x;
    const int col = t & 63, r0 = (t >> 6) * 16;
    float v[16];
#pragma unroll
    for (int i = 0; i < 16; ++i) v[i] = src[(size_t)(r0 + i) * ldr + col];
#pragma unroll
    for (int h = 0; h < 2; ++h) {
        const int rr = r0 + 8 * h;
        const int tile = (rr >> 5) * mr + (col >> 4) * mc;
        uint4 u = make_uint4(cvt2(v[8*h+0],v[8*h+1]), cvt2(v[8*h+2],v[8*h+3]),
                             cvt2(v[8*h+4],v[8*h+5]), cvt2(v[8*h+6],v[8*h+7]));
        *(uint4*)&dst[tile*TILE + ((col&15) + 16*((rr&31)>>3))*8] = u;
    }
}

__global__ __launch_bounds__(256, 4) void chunk_out(
    const float* __restrict__ gq, const float* __restrict__ gqr,
    const float* __restrict__ gk, const float* __restrict__ gkr,
    const float* __restrict__ gv, const float* __restrict__ ws,
    float* __restrict__ out)
{
    __shared__ unsigned short sm[SM3_TOT];
    const int t = threadIdx.x;
    const int blk = blockIdx.x, chunk = blk >> 1, rbk = blk & 1;
    const int bh = chunk >> 6, c = chunk & 63;
    const size_t gbase = (size_t)bh * N_ * D_ + (size_t)c * C_ * D_;
    const float* st = ws + (size_t)chunk * STATE;
    const int w = t >> 6, lane = t & 63, lg = lane >> 4, lm = lane & 15;
    const int col = t & 63, r0g = (t >> 6) * 16;

    // ---- Q, Qr direct to A-frag registers ----
    bf16x8 qf[2][2];
    {
        const size_t qrow = gbase + (size_t)(rbk*64 + w*16 + lm) * D_;
#pragma unroll
        for (int td = 0; td < 2; ++td) {
            const size_t g = qrow + td*32 + lg*8;
            float4 a = *(const float4*)(gq + g),  b = *(const float4*)(gq + g + 4);
            float4 ar= *(const float4*)(gqr + g), br= *(const float4*)(gqr + g + 4);
            U16x8 u;
            u.u = make_uint4(cvt2(a.x,a.y), cvt2(a.z,a.w), cvt2(b.x,b.y), cvt2(b.z,b.w));
            qf[0][td] = u.v;
            u.u = make_uint4(cvt2(ar.x,ar.y), cvt2(ar.z,ar.w), cvt2(br.x,br.y), cvt2(br.z,br.w));
            qf[1][td] = u.v;
        }
    }

    // ---- K/Kr register staging (prefetchable) ----
    float4 kf4[4], rf4[4];
    auto load_kr = [&](int mh){
        const size_t g = gbase + (size_t)(mh*64 + (t >> 2)) * D_ + (t & 3)*16;
#pragma unroll
        for (int i = 0; i < 4; ++i) {
            kf4[i] = *(const float4*)(gk  + g + i*4);
            rf4[i] = *(const float4*)(gkr + g + i*4);
        }
    };
    auto write_row_reg = [&](const float4* f, int baseT, int mr, int mc){
        const int r = t >> 2, c0 = (t & 3) * 16;
        const int tile = (r >> 4) * mr + (c0 >> 5) * mc;
        const int g0 = (c0 & 31) >> 3;
        uint4 u0 = make_uint4(cvt2(f[0].x,f[0].y), cvt2(f[0].z,f[0].w),
                              cvt2(f[1].x,f[1].y), cvt2(f[1].z,f[1].w));
        uint4 u1 = make_uint4(cvt2(f[2].x,f[2].y), cvt2(f[2].z,f[2].w),
                              cvt2(f[3].x,f[3].y), cvt2(f[3].z,f[3].w));
        *(uint4*)&sm[(baseT + tile)*TILE + ((r&15) + 16* g0   )*8] = u0;
        *(uint4*)&sm[(baseT + tile)*TILE + ((r&15) + 16*(g0+1))*8] = u1;
    };
    auto stage_v = [&](int mh){
        float vv[16];
        const size_t base = gbase + (size_t)(mh*64 + r0g) * D_ + col;
#pragma unroll
        for (int i = 0; i < 16; ++i) vv[i] = gv[base + (size_t)i * D_];
#pragma unroll
        for (int hh = 0; hh < 2; ++hh) {
            const int rr = r0g + 8*hh;
            const int tile = (rr >> 5) * 4 + (col >> 4);
            uint4 u = make_uint4(cvt2(vv[8*hh+0],vv[8*hh+1]), cvt2(vv[8*hh+2],vv[8*hh+3]),
                                 cvt2(vv[8*hh+4],vv[8*hh+5]), cvt2(vv[8*hh+6],vv[8*hh+7]));
            *(uint4*)&sm[(SV0 + tile)*TILE + ((col&15) + 16*((rr&31)>>3))*8] = u;
        }
    };

    f32x4 oacc[4];
#pragma unroll
    for (int te = 0; te < 4; ++te) oacc[te] = f32x4{0.f,0.f,0.f,0.f};
    f32x4 acc4 = f32x4{0.f,0.f,0.f,0.f};
    float denp[4] = {0.f,0.f,0.f,0.f};

    const int TMmax = rbk * 4 + w;
    const int TKtop = ((TMmax >> 1) << 1) + 1;

    auto compute_half = [&](int mh){
#pragma unroll
        for (int tm = 0; tm < 4; ++tm) {
            const int TM = mh*4 + tm;
            if (TM <= TKtop) {
                f32x4 a = f32x4{0.f,0.f,0.f,0.f};
                if (TM <= TMmax) {
                    a = MFMA(qf[0][0], KFRG(0,0,tm), a);
                    a = MFMA(qf[0][1], KFRG(0,1,tm), a);
                    a = MFMA(qf[1][0], KFRG(1,0,tm), a);
                    a = MFMA(qf[1][1], KFRG(1,1,tm), a);
                }
                const int mb = TM * 16 + lm;
                const int pb = (SP0 + w*2 + (tm>>1))*TILE
                             + 16*((tm&1)*2 + (lm>>3))*8 + (lm&7);
#pragma unroll
                for (int r = 0; r < 4; ++r) {
                    const int ng = rbk*64 + w*16 + lg*4 + r;
                    const float pv = (TM <= TMmax && mb <= ng) ? a[r] : 0.f;
                    denp[r] += pv;
                    sm[pb + (lg*4 + r)*8] = cvt1(pv);
                }
            }
        }
#pragma unroll
        for (int tk = 0; tk < 2; ++tk) {
            const int TK = mh*2 + tk;
            if (TK <= (TMmax >> 1)) {
                bf16x8 pa = *(const bf16x8*)&sm[(SP0 + w*2+tk)*TILE + lane*8];
#pragma unroll
                for (int te = 0; te < 4; ++te)
                    oacc[te] = MFMA(pa, VFRG(tk,te), oacc[te]);
            }
        }
    };

    // ---- half 0 ----
    load_kr(0);
    write_row_reg(kf4, SK0, 1, 4);
    write_row_reg(rf4, SK0 + 8, 1, 4);
    stage_v(0);
    if (rbk) load_kr(1);                 // prefetch half-1 K/Kr under half-0 compute
    __syncthreads();
    compute_half(0);
    // ---- half 1 (rbk==1 only) ----
    if (rbk) {
        __syncthreads();
        write_row_reg(kf4, SK0, 1, 4);
        write_row_reg(rf4, SK0 + 8, 1, 4);
        stage_v(1);
        __syncthreads();
        compute_half(1);
    }

    // ---- carry: stage Sc/Scr (+aug col kc/krc), GEMM ----
    __syncthreads();                      // PV reads of SK0/SV0 done
    stage_colT(st + 128,        64, sm + SSC0*TILE,             5, 1);
    stage_colT(st + 128 + 4096, 64, sm + (SSC0 + 10)*TILE,      5, 1);
    for (int i = t; i < 4 * 260; i += 256) {   // zero 4 aug tiles
        const int tile = i / 260, off = i % 260;
        const int ten = tile >> 1, td = tile & 1;
        *(unsigned*)&sm[(SSC0 + ten*10 + td*5 + 4)*TILE + off*2] = 0u;
    }
    __syncthreads();
    if (t < 128) {                        // aug col0 = kc / krc
        const int ten = t >> 6, d = t & 63;
        sm[(SSC0 + ten*10 + (d>>5)*5 + 4)*TILE + (16*((d&31)>>3))*8 + (d&7)] = cvt1(st[t]);
    }
    __syncthreads();
#pragma unroll
    for (int td = 0; td < 2; ++td) {
#pragma unroll
        for (int te = 0; te < 4; ++te) {
            oacc[te] = MFMA(qf[0][td], SCFRG(0,td,te), oacc[te]);
            oacc[te] = MFMA(qf[1][td], SCFRG(1,td,te), oacc[te]);
        }
        acc4 = MFMA(qf[0][td], SCFRG(0,td,4), acc4);
        acc4 = MFMA(qf[1][td], SCFRG(1,td,4), acc4);
    }

    // ---- denominator, scale, store ----
    const size_t orow = (size_t)bh * N_ * E_ + (size_t)(c * C_ + rbk * 64 + w * 16) * E_;
#pragma unroll
    for (int r = 0; r < 4; ++r) {
        float d = denp[r];
        d += __shfl_xor(d, 1); d += __shfl_xor(d, 2);
        d += __shfl_xor(d, 4); d += __shfl_xor(d, 8);
        const float dc = __shfl(acc4[r], lane & 48);
        const float dinv = 1.0f / (d + dc + EPS_);
        const size_t ob = orow + (size_t)(lg * 4 + r) * E_ + lm;
        out[ob +  0] = oacc[0][r] * dinv;
        out[ob + 16] = oacc[1][r] * dinv;
        out[ob + 32] = oacc[2][r] * dinv;
        out[ob + 48] = oacc[3][r] * dinv;
    }
}
#undef KFRG
#undef VFRG
#undef SCFRG

extern "C" void kernel_launch(void* const* d_in, const int* in_sizes, int n_in,
                              void* d_out, int out_size, void* d_ws, size_t ws_size,
                              hipStream_t stream) {
    const float* q  = (const float*)d_in[0];
    const float* k  = (const float*)d_in[1];
    const float* qr = (const float*)d_in[2];
    const float* kr = (const float*)d_in[3];
    const float* v  = (const float*)d_in[4];
    float* out = (float*)d_out;
    float* ws  = (float*)d_ws;

    chunk_states<<<NCHUNKS, 256, 0, stream>>>(k, kr, v, ws);
    scan_states<<<dim3(BH, 9), 256, 0, stream>>>(ws, out);
    chunk_out<<<NCHUNKS * 2, 256, 0, stream>>>(q, qr, k, kr, v, ws, out);
}

// Round 4
// 392.414 us; speedup vs baseline: 6.1601x; 1.0152x over previous
//
#include <hip/hip_runtime.h>

// Chunked causal linear attention. B=4 H=8 N=8192 D=E=64 C=128.
//  1) chunk_states (bf16 MFMA, hi/lo split): per-chunk {sumK, sumKr, K^T V, Kr^T V} -> ws (f32)
//  2) scan_states  (f32, float4): exclusive prefix over 64 chunks per (b,h); totals -> d_out tail
//  3) chunk_out    (bf16 MFMA, 1 block = 1 chunk, 512 thr): P = tril(QK^T + QrKr^T);
//       out = (P V + Q Sc + Qr Scr) / (rowsum(P) + q.kc + qr.krc + eps)
// ws requirement: 2048 * 8320 * 4 = 68,157,440 bytes.

typedef short bf16x8 __attribute__((ext_vector_type(8)));
typedef float f32x4  __attribute__((ext_vector_type(4)));
union U16x8 { bf16x8 v; uint4 u; };

constexpr int BH = 32;
constexpr int N_ = 8192, D_ = 64, E_ = 64, C_ = 128;
constexpr int NC = 64;
constexpr int NCHUNKS = BH * NC;     // 2048
constexpr int STATE = 8320;          // 64+64+4096+4096 floats per chunk-state
#define EPS_ 1e-6f

constexpr size_t OUT_ELEMS = (size_t)BH * N_ * E_;
constexpr size_t ZOFF  = OUT_ELEMS;
constexpr size_t SOFF  = ZOFF  + (size_t)BH * 64;
constexpr size_t ZROFF = SOFF  + (size_t)BH * 4096;
constexpr size_t SROFF = ZROFF + (size_t)BH * 64;

// ---- bf16 helpers (RNE) ----
__device__ inline unsigned cvt2(float a, float b){
    union { float f; unsigned u; } x, y; x.f = a; y.f = b;
    unsigned lo = (x.u + 0x7fffu + ((x.u >> 16) & 1u)) >> 16;
    unsigned hi = (y.u + 0x7fffu + ((y.u >> 16) & 1u)) >> 16;
    return lo | (hi << 16);
}
__device__ inline unsigned short cvt1(float a){
    union { float f; unsigned u; } x; x.f = a;
    return (unsigned short)((x.u + 0x7fffu + ((x.u >> 16) & 1u)) >> 16);
}
__device__ inline float bflo(float x, unsigned short hi){
    union { unsigned u; float f; } h; h.u = ((unsigned)hi) << 16;
    return x - h.f;
}

constexpr int TILE = 520;            // one 16x32 MFMA operand tile (512 bf16 + pad)
#define MFMA(A,B,C) __builtin_amdgcn_mfma_f32_16x16x32_bf16((A),(B),(C),0,0,0)

// ---------------- Phase 1: per-chunk state totals (MFMA hi/lo) ----------------
// A-frags: K^T, Kr^T (hi+lo); B-frags: V (hi+lo); ones-column frag in registers.
// S = Ah*Bh + Al*Bh + Ah*Bl ; sums = (Ah+Al)*ones. f32 accum, f32 out to ws.
constexpr int AKH = 0, AKL = 8, ARH = 16, ARL = 24, BVH = 32, BVL = 40;
constexpr int SM1_TOT = 48 * TILE;   // 49,920 B

__global__ __launch_bounds__(256, 3) void chunk_states(
    const float* __restrict__ gk, const float* __restrict__ gkr,
    const float* __restrict__ gv, float* __restrict__ ws)
{
    __shared__ unsigned short sm[SM1_TOT];
    const int t = threadIdx.x;
    const int cid = blockIdx.x, bh = cid >> 6, c = cid & 63;
    const size_t gbase = (size_t)bh * N_ * D_ + (size_t)c * C_ * D_;
    const int w = t >> 6, lane = t & 63, lg = lane >> 4, lm = lane & 15;
    const int col = t & 63, r0g = (t >> 6) * 16;

    // ones-column B-frag: col 0 = 1.0 -> lanes with lm==0 hold 1.0 in all slots
    U16x8 uo;
    uo.u = (lm == 0) ? make_uint4(0x3F803F80u,0x3F803F80u,0x3F803F80u,0x3F803F80u)
                     : make_uint4(0u,0u,0u,0u);
    const bf16x8 onesf = uo.v;

    float kv[16], krv[16], vv[16];
    auto load_half = [&](int h){
        const size_t base = gbase + (size_t)(h * 64 + r0g) * D_ + col;
#pragma unroll
        for (int i = 0; i < 16; ++i) {
            kv [i] = gk [base + (size_t)i * D_];
            krv[i] = gkr[base + (size_t)i * D_];
            vv [i] = gv [base + (size_t)i * D_];
        }
    };
    auto write_hl = [&](const float* v16, int hiT, int loT){
#pragma unroll
        for (int hh = 0; hh < 2; ++hh) {
            const int rr = r0g + 8 * hh;
            const int tile = (rr >> 5) * 4 + (col >> 4);
            const int off = ((col & 15) + 16 * ((rr & 31) >> 3)) * 8;
            unsigned short h8[8]; float l8[8];
#pragma unroll
            for (int j = 0; j < 8; ++j) {
                h8[j] = cvt1(v16[8*hh + j]);
                l8[j] = bflo(v16[8*hh + j], h8[j]);
            }
            uint4 uh = make_uint4((unsigned)h8[0] | ((unsigned)h8[1] << 16),
                                  (unsigned)h8[2] | ((unsigned)h8[3] << 16),
                                  (unsigned)h8[4] | ((unsigned)h8[5] << 16),
                                  (unsigned)h8[6] | ((unsigned)h8[7] << 16));
            uint4 ul = make_uint4(cvt2(l8[0],l8[1]), cvt2(l8[2],l8[3]),
                                  cvt2(l8[4],l8[5]), cvt2(l8[6],l8[7]));
            *(uint4*)&sm[(hiT + tile) * TILE + off] = uh;
            *(uint4*)&sm[(loT + tile) * TILE + off] = ul;
        }
    };

    f32x4 aK[4], aR[4], sK = {0.f,0.f,0.f,0.f}, sR = {0.f,0.f,0.f,0.f};
#pragma unroll
    for (int e = 0; e < 4; ++e) { aK[e] = f32x4{0.f,0.f,0.f,0.f}; aR[e] = f32x4{0.f,0.f,0.f,0.f}; }

    auto FR = [&](int tile)->bf16x8 { return *(const bf16x8*)&sm[tile * TILE + lane * 8]; };
    auto compute = [&](){
#pragma unroll
        for (int kt = 0; kt < 2; ++kt) {
            bf16x8 ah = FR(AKH + kt*4 + w), al = FR(AKL + kt*4 + w);
            bf16x8 rh = FR(ARH + kt*4 + w), rl = FR(ARL + kt*4 + w);
            sK = MFMA(ah, onesf, sK); sK = MFMA(al, onesf, sK);
            sR = MFMA(rh, onesf, sR); sR = MFMA(rl, onesf, sR);
#pragma unroll
            for (int et = 0; et < 4; ++et) {
                bf16x8 bh = FR(BVH + kt*4 + et), bl = FR(BVL + kt*4 + et);
                aK[et] = MFMA(ah, bh, aK[et]);
                aK[et] = MFMA(al, bh, aK[et]);
                aK[et] = MFMA(ah, bl, aK[et]);
                aR[et] = MFMA(rh, bh, aR[et]);
                aR[et] = MFMA(rl, bh, aR[et]);
                aR[et] = MFMA(rh, bl, aR[et]);
            }
        }
    };

    load_half(0);
    write_hl(kv, AKH, AKL); write_hl(krv, ARH, ARL); write_hl(vv, BVH, BVL);
    load_half(1);                       // prefetch into regs while half-0 computes
    __syncthreads();
    compute();
    __syncthreads();
    write_hl(kv, AKH, AKL); write_hl(krv, ARH, ARL); write_hl(vv, BVH, BVL);
    __syncthreads();
    compute();

    float* st = ws + (size_t)cid * STATE;
    if (lm == 0) {
#pragma unroll
        for (int r = 0; r < 4; ++r) {
            const int d = w*16 + lg*4 + r;
            st[d]      = sK[r];
            st[64 + d] = sR[r];
        }
    }
    float* cs  = st + 128;
    float* csr = st + 128 + 4096;
#pragma unroll
    for (int et = 0; et < 4; ++et)
#pragma unroll
        for (int r = 0; r < 4; ++r) {
            const int d = w*16 + lg*4 + r, e = et*16 + lm;
            cs [d*64 + e] = aK[et][r];
            csr[d*64 + e] = aR[et][r];
        }
}

// ---------------- Phase 2: exclusive scan, float4 ----------------
__global__ __launch_bounds__(256) void scan_states(float* __restrict__ ws, float* __restrict__ out)
{
    const int bh = blockIdx.x;
    const int j4 = blockIdx.y * 256 + threadIdx.x;
    if (j4 >= STATE / 4) return;        // 2080
    float4 run = make_float4(0.f, 0.f, 0.f, 0.f);
    float* base = ws + (size_t)bh * NC * STATE + (size_t)j4 * 4;
#pragma unroll 8
    for (int c = 0; c < NC; ++c) {
        float4 x = *(float4*)(base + (size_t)c * STATE);
        *(float4*)(base + (size_t)c * STATE) = run;
        run.x += x.x; run.y += x.y; run.z += x.z; run.w += x.w;
    }
    const int j = j4 * 4;
    float* dst;
    if (j < 64)        dst = out + ZOFF  + (size_t)bh*64   + j;
    else if (j < 128)  dst = out + ZROFF + (size_t)bh*64   + (j - 64);
    else if (j < 4224) dst = out + SOFF  + (size_t)bh*4096 + (j - 128);
    else               dst = out + SROFF + (size_t)bh*4096 + (j - 4224);
    *(float4*)dst = run;
}

// ---------------- Phase 3: MFMA chunk output (1 block = 1 chunk, 512 thr) ----------------
// LDS tiles: SK0=0 (K,Kr B-frags, 16), SV0=16 (V B-frags, 8), SP0=24 (P A-frags, 16).
// Carry Sc/Scr (16 tiles, ten*8+td*4+te) aliases SK0/SV0 after the mh loop.
constexpr int SK0 = 0, SV0 = 16, SP0 = 24;
constexpr int SM3_TOT = 40 * TILE;     // 41,600 B

#define KFRG(ten,td,tm)  (*(const bf16x8*)&sm[(SK0 + ((ten)*2+(td))*4+(tm))*TILE + lane*8])
#define VFRG(tk,te)      (*(const bf16x8*)&sm[(SV0 + (tk)*4+(te))*TILE + lane*8])
#define SCFRG(ten,td,te) (*(const bf16x8*)&sm[((ten)*8+(td)*4+(te))*TILE + lane*8])

__global__ __launch_bounds__(512, 6) void chunk_out(
    const float* __restrict__ gq, const float* __restrict__ gqr,
    const float* __restrict__ gk, const float* __restrict__ gkr,
    const float* __restrict__ gv, const float* __restrict__ ws,
    float* __restrict__ out)
{
    __shared__ unsigned short sm[SM3_TOT];
    const int t = threadIdx.x;
    const int chunk = blockIdx.x;
    const int bh = chunk >> 6, c = chunk & 63;
    const size_t gbase = (size_t)bh * N_ * D_ + (size_t)c * C_ * D_;
    const float* st = ws + (size_t)chunk * STATE;
    const int w = t >> 6, lane = t & 63, lg = lane >> 4, lm = lane & 15;

    // ---- Q, Qr direct to A-frag registers (wave w owns rows 16w..16w+15) ----
    bf16x8 qf[2][2];
    {
        const size_t qrow = gbase + (size_t)(w*16 + lm) * D_;
#pragma unroll
        for (int td = 0; td < 2; ++td) {
            const size_t g = qrow + td*32 + lg*8;
            float4 a = *(const float4*)(gq + g),  b = *(const float4*)(gq + g + 4);
            float4 ar= *(const float4*)(gqr + g), br= *(const float4*)(gqr + g + 4);
            U16x8 u;
            u.u = make_uint4(cvt2(a.x,a.y), cvt2(a.z,a.w), cvt2(b.x,b.y), cvt2(b.z,b.w));
            qf[0][td] = u.v;
            u.u = make_uint4(cvt2(ar.x,ar.y), cvt2(ar.z,ar.w), cvt2(br.x,br.y), cvt2(br.z,br.w));
            qf[1][td] = u.v;
        }
    }

    // ---- carry prefetch into registers (T14: issue early, write late) ----
    float sc8[8], scr8[8];
    {
        const int col = t & 63, r0 = (t >> 6) * 8;
        const float* p  = st + 128        + (size_t)r0 * 64 + col;
        const float* pr = st + 128 + 4096 + (size_t)r0 * 64 + col;
#pragma unroll
        for (int i = 0; i < 8; ++i) { sc8[i] = p[i*64]; scr8[i] = pr[i*64]; }
    }

    f32x4 oacc[4];
#pragma unroll
    for (int te = 0; te < 4; ++te) oacc[te] = f32x4{0.f,0.f,0.f,0.f};
    f32x4 acc4 = f32x4{0.f,0.f,0.f,0.f};
    float denp[4] = {0.f,0.f,0.f,0.f};

    const int TKtop = ((w >> 1) << 1) + 1;

    for (int mh = 0; mh < 2; ++mh) {
        __syncthreads();                 // previous half's K/V reads done
        {   // stage K/Kr: 8 floats per thread
            const int r = t >> 3, c0 = (t & 7) * 8;
            const size_t g = gbase + (size_t)(mh*64 + r) * D_ + c0;
            const int tb  = (r >> 4) + (c0 >> 5) * 4;
            const int off = ((r & 15) + 16 * ((c0 & 31) >> 3)) * 8;
            float4 a = *(const float4*)(gk + g), b = *(const float4*)(gk + g + 4);
            *(uint4*)&sm[(SK0 + tb)*TILE + off] =
                make_uint4(cvt2(a.x,a.y), cvt2(a.z,a.w), cvt2(b.x,b.y), cvt2(b.z,b.w));
            a = *(const float4*)(gkr + g); b = *(const float4*)(gkr + g + 4);
            *(uint4*)&sm[(SK0 + 8 + tb)*TILE + off] =
                make_uint4(cvt2(a.x,a.y), cvt2(a.z,a.w), cvt2(b.x,b.y), cvt2(b.z,b.w));
        }
        {   // stage V: 8 col-strided floats per thread
            const int col = t & 63, r0 = (t >> 6) * 8;
            const size_t vb = gbase + (size_t)(mh*64 + r0) * D_ + col;
            float vv[8];
#pragma unroll
            for (int i = 0; i < 8; ++i) vv[i] = gv[vb + (size_t)i * D_];
            const int tb  = (r0 >> 5) * 4 + (col >> 4);
            const int off = ((col & 15) + 16 * ((r0 & 31) >> 3)) * 8;
            *(uint4*)&sm[(SV0 + tb)*TILE + off] =
                make_uint4(cvt2(vv[0],vv[1]), cvt2(vv[2],vv[3]),
                           cvt2(vv[4],vv[5]), cvt2(vv[6],vv[7]));
        }
        __syncthreads();
        if (w >= mh * 4) {
            // ---- P tiles: compute, mask, rowsum, restage as PV A-frags ----
#pragma unroll
            for (int tm = 0; tm < 4; ++tm) {
                const int TM = mh*4 + tm;
                if (TM <= TKtop) {
                    f32x4 a = f32x4{0.f,0.f,0.f,0.f};
                    if (TM <= w) {
                        a = MFMA(qf[0][0], KFRG(0,0,tm), a);
                        a = MFMA(qf[0][1], KFRG(0,1,tm), a);
                        a = MFMA(qf[1][0], KFRG(1,0,tm), a);
                        a = MFMA(qf[1][1], KFRG(1,1,tm), a);
                    }
                    const int mb = TM * 16 + lm;
                    const int pb = (SP0 + w*2 + (tm>>1))*TILE
                                 + 16*((tm&1)*2 + (lm>>3))*8 + (lm&7);
#pragma unroll
                    for (int r = 0; r < 4; ++r) {
                        const int ng = w*16 + lg*4 + r;
                        const float pv = (TM <= w && mb <= ng) ? a[r] : 0.f;
                        denp[r] += pv;
                        sm[pb + (lg*4 + r)*8] = cvt1(pv);
                    }
                }
            }
            // ---- PV: out += P_half * V_half ----
#pragma unroll
            for (int tk = 0; tk < 2; ++tk) {
                if (mh*2 + tk <= (w >> 1)) {
                    bf16x8 pa = *(const bf16x8*)&sm[(SP0 + w*2 + tk)*TILE + lane*8];
#pragma unroll
                    for (int te = 0; te < 4; ++te)
                        oacc[te] = MFMA(pa, VFRG(tk,te), oacc[te]);
                }
            }
        }
    }

    // ---- carry: write prefetched Sc/Scr to LDS (aliases SK0/SV0), GEMM ----
    __syncthreads();
    {
        const int col = t & 63, r0 = (t >> 6) * 8;
        const int tb  = (r0 >> 5) * 4 + (col >> 4);
        const int off = ((col & 15) + 16 * ((r0 & 31) >> 3)) * 8;
        *(uint4*)&sm[tb*TILE + off] =
            make_uint4(cvt2(sc8[0],sc8[1]), cvt2(sc8[2],sc8[3]),
                       cvt2(sc8[4],sc8[5]), cvt2(sc8[6],sc8[7]));
        *(uint4*)&sm[(8 + tb)*TILE + off] =
            make_uint4(cvt2(scr8[0],scr8[1]), cvt2(scr8[2],scr8[3]),
                       cvt2(scr8[4],scr8[5]), cvt2(scr8[6],scr8[7]));
    }
    __syncthreads();
    // aug B-frags (col 0 = kc / krc) built in registers
    bf16x8 augf[2][2];
#pragma unroll
    for (int ten = 0; ten < 2; ++ten)
#pragma unroll
        for (int td = 0; td < 2; ++td) {
            const float* ap = st + ten*64 + td*32 + lg*8;
            float4 a = *(const float4*)ap, b = *(const float4*)(ap + 4);
            U16x8 u;
            u.u = make_uint4(cvt2(a.x,a.y), cvt2(a.z,a.w), cvt2(b.x,b.y), cvt2(b.z,b.w));
            if (lm != 0) u.u = make_uint4(0u,0u,0u,0u);
            augf[ten][td] = u.v;
        }
#pragma unroll
    for (int td = 0; td < 2; ++td) {
#pragma unroll
        for (int te = 0; te < 4; ++te) {
            oacc[te] = MFMA(qf[0][td], SCFRG(0,td,te), oacc[te]);
            oacc[te] = MFMA(qf[1][td], SCFRG(1,td,te), oacc[te]);
        }
        acc4 = MFMA(qf[0][td], augf[0][td], acc4);
        acc4 = MFMA(qf[1][td], augf[1][td], acc4);
    }

    // ---- denominator, scale, store ----
    const size_t orow = (size_t)bh * N_ * E_ + (size_t)(c * C_ + w * 16) * E_;
#pragma unroll
    for (int r = 0; r < 4; ++r) {
        float d = denp[r];
        d += __shfl_xor(d, 1); d += __shfl_xor(d, 2);
        d += __shfl_xor(d, 4); d += __shfl_xor(d, 8);
        const float dc = __shfl(acc4[r], lane & 48);
        const float dinv = 1.0f / (d + dc + EPS_);
        const size_t ob = orow + (size_t)(lg * 4 + r) * E_ + lm;
        out[ob +  0] = oacc[0][r] * dinv;
        out[ob + 16] = oacc[1][r] * dinv;
        out[ob + 32] = oacc[2][r] * dinv;
        out[ob + 48] = oacc[3][r] * dinv;
    }
}
#undef KFRG
#undef VFRG
#undef SCFRG

extern "C" void kernel_launch(void* const* d_in, const int* in_sizes, int n_in,
                              void* d_out, int out_size, void* d_ws, size_t ws_size,
                              hipStream_t stream) {
    const float* q  = (const float*)d_in[0];
    const float* k  = (const float*)d_in[1];
    const float* qr = (const float*)d_in[2];
    const float* kr = (const float*)d_in[3];
    const float* v  = (const float*)d_in[4];
    float* out = (float*)d_out;
    float* ws  = (float*)d_ws;

    chunk_states<<<NCHUNKS, 256, 0, stream>>>(k, kr, v, ws);
    scan_states<<<dim3(BH, 9), 256, 0, stream>>>(ws, out);
    chunk_out<<<NCHUNKS, 512, 0, stream>>>(q, qr, k, kr, v, ws, out);
}